// Round 5
// baseline (3519.384 us; speedup 1.0000x reference)
//
#include <hip/hip_runtime.h>
#include <hip/hip_bf16.h>

#define TT 512
#define BB 64
#define DD 512
#define HH 512
#define NWG 64
#define NTH 512
#define PSTR 36                          // padded LDS row stride: <=2-way banks
#define LDS_BYTES (8 * BB * PSTR * 4)    // 73728 B, dynamic shared
#define HB_ELEMS (BB * HH)               // u32 elems per parity buffer
#define SPIN_MAX 200000

typedef short bf16x8 __attribute__((ext_vector_type(8)));
typedef float f32x4 __attribute__((ext_vector_type(4)));
typedef float float4_ __attribute__((ext_vector_type(4)));
typedef unsigned int u32x4 __attribute__((ext_vector_type(4)));
typedef unsigned short ushort_t;

__device__ __forceinline__ unsigned f2bf(float f) {
    unsigned u = __float_as_uint(f);
    return (u + 0x7fffu + ((u >> 16) & 1u)) >> 16;   // RNE
}

__device__ __forceinline__ bf16x8 cvt8(const float* p) {
    float4_ u0 = *(const float4_*)(p);
    float4_ u1 = *(const float4_*)(p + 4);
    bf16x8 a;
    a[0] = (short)f2bf(u0.x); a[1] = (short)f2bf(u0.y);
    a[2] = (short)f2bf(u0.z); a[3] = (short)f2bf(u0.w);
    a[4] = (short)f2bf(u1.x); a[5] = (short)f2bf(u1.y);
    a[6] = (short)f2bf(u1.z); a[7] = (short)f2bf(u1.w);
    return a;
}

__device__ __forceinline__ float fast_sigmoid(float x) {
    return __builtin_amdgcn_rcpf(1.f + __expf(-x));
}
__device__ __forceinline__ float fast_tanh(float x) {
    return 2.f * __builtin_amdgcn_rcpf(1.f + __expf(-2.f * x)) - 1.f;
}

// write-through coherent dword store (visible at the shared coherence point)
__device__ __forceinline__ void store_coh4(unsigned* p, unsigned v) {
    asm volatile("global_store_dword %0, %1, off sc0 sc1" :: "v"(p), "v"(v) : "memory");
}

// ---------------- LSTM kernel ----------------
// MODE 1: persistent, barrier-free tagged h-exchange via d_ws (u32 = tag<<16 | bf16).
// MODE 2: one step per launch, h read from out (f32) — zero-workspace fallback.
//
// 64 WGs x 512 threads (8 waves). WG wg owns h-cols [wg*8, wg*8+8) for all 64
// batch rows (32 gate cols). Wave w handles K-steps {2w, 2w+1} (of 16) for BOTH
// the x half and the h half; computes 4 m-tiles x 2 n-tiles; partials reduced
// 8-way through LDS; activation thread (b,j) sums.
//
// hbuf32 layout: [parity][hcol>>3][row][hcol&7]  (u32 each)
//   producer idx = wg*512 + tid; consumer chunk = 8 consecutive u32.
//
// Race-freedom of parity reuse: WG A publishes h(t+2) into parity p=(t+1)&1
// only after consuming all of h(t+1); any WG publishing h(t+1) already finished
// reading h(t) from p. So overwrite of h(t) happens strictly after every
// consumer of h(t) is done.
template<int MODE>
__global__ __launch_bounds__(NTH)
void lstm_kernel(const float* __restrict__ x,
                 const float* __restrict__ Wf, const float* __restrict__ bfp,
                 const float* __restrict__ Wi, const float* __restrict__ bip,
                 const float* __restrict__ Wg, const float* __restrict__ bgp,
                 const float* __restrict__ Wo, const float* __restrict__ bop,
                 float* __restrict__ out,
                 unsigned* __restrict__ hbuf32,
                 int t0, int t1)
{
    const int tid = threadIdx.x;
    const int wg  = blockIdx.x;
    const int l   = tid & 63;
    const int w   = tid >> 6;          // wave 0..7
    const int l15 = l & 15;
    const int lg  = l >> 4;            // 0..3
    const int sub = lg * 8;            // k sub-offset within a 32-wide k-step

    extern __shared__ float Pdyn[];
    float (*P)[BB * PSTR] = (float (*)[BB * PSTR])Pdyn;   // [8][64*36]

    // ---- weights for this wave: 2 k-steps x 2 n-tiles, x-half and h-half ----
    bf16x8 xwt[2][2], hwt[2][2];
    {
        #pragma unroll
        for (int nt = 0; nt < 2; ++nt) {
            int n = nt * 16 + l15;                       // 0..31 panel col
            const float* wmat = (n >> 3) == 0 ? Wf :
                                ((n >> 3) == 1 ? Wi :
                                ((n >> 3) == 2 ? Wg : Wo));
            const float* wrow = wmat + (size_t)(wg * 8 + (n & 7)) * (DD + HH);
            #pragma unroll
            for (int ks2 = 0; ks2 < 2; ++ks2) {
                int k0 = (2 * w + ks2) * 32 + sub;
                xwt[ks2][nt] = cvt8(wrow + k0);          // x part: k in [0,512)
                hwt[ks2][nt] = cvt8(wrow + DD + k0);     // h part: k in [512,1024)
            }
        }
    }

    // activation mapping: thread owns (batch b_act, hcol wg*8 + j_act)
    const int b_act = tid >> 3;        // 0..63
    const int j_act = tid & 7;         // 0..7
    const float bfv = bfp[wg * 8 + j_act];
    const float biv = bip[wg * 8 + j_act];
    const float bgv = bgp[wg * 8 + j_act];
    const float bov = bop[wg * 8 + j_act];

    float c_state, h_last = 0.f;
    if constexpr (MODE == 1) {
        c_state = 0.f;
    } else {
        c_state = (t0 == 0) ? 0.f
                : out[(size_t)TT * BB * HH + BB * HH + (size_t)b_act * HH + wg * 8 + j_act];
    }

    // consumer chunk offsets (u32 units): [ks2][mt]
    unsigned hoff[2][4];
    #pragma unroll
    for (int ks2 = 0; ks2 < 2; ++ks2)
        #pragma unroll
        for (int mt = 0; mt < 4; ++mt)
            hoff[ks2][mt] = (unsigned)(((2 * w + ks2) * 4 + lg) * 512 + (mt * 16 + l15) * 8);

    int deadf = 0;

    for (int t = t0; t < t1; ++t) {
        // ---- x-half A fragments (issued early; latency hides under poll) ----
        bf16x8 xa[2][4];
        #pragma unroll
        for (int ks2 = 0; ks2 < 2; ++ks2)
            #pragma unroll
            for (int mt = 0; mt < 4; ++mt) {
                const float* xp = x + ((size_t)t * BB + mt * 16 + l15) * DD
                                + (2 * w + ks2) * 32 + sub;
                xa[ks2][mt] = cvt8(xp);
            }

        // ---- h-half A fragments ----
        bf16x8 hf[2][4];
        bool doH = (t > 0);
        if constexpr (MODE == 1) {
            if (doH && !deadf) {
                u32x4 raw[2][4][2];
                const unsigned tagv = (unsigned)t << 16;
                unsigned* hb = hbuf32 + (size_t)(t & 1) * HB_ELEMS;
                int it = 0;
                while (true) {
                    #pragma unroll
                    for (int ks2 = 0; ks2 < 2; ++ks2)
                        #pragma unroll
                        for (int mt = 0; mt < 4; ++mt) {
                            unsigned* p0 = hb + hoff[ks2][mt];
                            asm volatile("global_load_dwordx4 %0, %1, off sc0 sc1"
                                         : "=v"(raw[ks2][mt][0]) : "v"(p0));
                            asm volatile("global_load_dwordx4 %0, %1, off offset:16 sc0 sc1"
                                         : "=v"(raw[ks2][mt][1]) : "v"(p0));
                        }
                    asm volatile("s_waitcnt vmcnt(0)" ::: "memory");
                    __builtin_amdgcn_sched_barrier(0);
                    unsigned bad = 0;
                    #pragma unroll
                    for (int ks2 = 0; ks2 < 2; ++ks2)
                        #pragma unroll
                        for (int mt = 0; mt < 4; ++mt)
                            #pragma unroll
                            for (int hh = 0; hh < 2; ++hh) {
                                u32x4 v = raw[ks2][mt][hh];
                                bad |= (v.x ^ tagv); bad |= (v.y ^ tagv);
                                bad |= (v.z ^ tagv); bad |= (v.w ^ tagv);
                            }
                    if (__all((bad & 0xffff0000u) == 0u)) break;
                    if (++it > SPIN_MAX) { deadf = 1; break; }
                }
                // unpack low halves -> bf16x8 fragments
                #pragma unroll
                for (int ks2 = 0; ks2 < 2; ++ks2)
                    #pragma unroll
                    for (int mt = 0; mt < 4; ++mt) {
                        u32x4 r0 = raw[ks2][mt][0];
                        u32x4 r1 = raw[ks2][mt][1];
                        u32x4 pk;
                        pk.x = (r0.x & 0xffffu) | (r0.y << 16);
                        pk.y = (r0.z & 0xffffu) | (r0.w << 16);
                        pk.z = (r1.x & 0xffffu) | (r1.y << 16);
                        pk.w = (r1.z & 0xffffu) | (r1.w << 16);
                        hf[ks2][mt] = *(bf16x8*)&pk;
                    }
            }
            if (deadf) doH = false;
        } else {
            if (doH) {
                #pragma unroll
                for (int ks2 = 0; ks2 < 2; ++ks2)
                    #pragma unroll
                    for (int mt = 0; mt < 4; ++mt) {
                        const float* hp = out + ((size_t)(t - 1) * BB + mt * 16 + l15) * HH
                                        + (2 * w + ks2) * 32 + sub;
                        hf[ks2][mt] = cvt8(hp);
                    }
            }
        }

        // ---- MFMA: acc[mt][nt] over this wave's 2 k-steps (x and h halves) ----
        f32x4 acc[4][2];
        #pragma unroll
        for (int mt = 0; mt < 4; ++mt)
            #pragma unroll
            for (int nt = 0; nt < 2; ++nt)
                acc[mt][nt] = (f32x4){0.f, 0.f, 0.f, 0.f};
        #pragma unroll
        for (int ks2 = 0; ks2 < 2; ++ks2)
            #pragma unroll
            for (int mt = 0; mt < 4; ++mt) {
                acc[mt][0] = __builtin_amdgcn_mfma_f32_16x16x32_bf16(xa[ks2][mt], xwt[ks2][0], acc[mt][0], 0, 0, 0);
                acc[mt][1] = __builtin_amdgcn_mfma_f32_16x16x32_bf16(xa[ks2][mt], xwt[ks2][1], acc[mt][1], 0, 0, 0);
            }
        if (doH) {
            #pragma unroll
            for (int ks2 = 0; ks2 < 2; ++ks2)
                #pragma unroll
                for (int mt = 0; mt < 4; ++mt) {
                    acc[mt][0] = __builtin_amdgcn_mfma_f32_16x16x32_bf16(hf[ks2][mt], hwt[ks2][0], acc[mt][0], 0, 0, 0);
                    acc[mt][1] = __builtin_amdgcn_mfma_f32_16x16x32_bf16(hf[ks2][mt], hwt[ks2][1], acc[mt][1], 0, 0, 0);
                }
        }

        // ---- stage partials: P[w] = full 64x32 partial for this wave's K ----
        #pragma unroll
        for (int mt = 0; mt < 4; ++mt)
            #pragma unroll
            for (int nt = 0; nt < 2; ++nt)
                #pragma unroll
                for (int r = 0; r < 4; ++r)
                    P[w][(mt * 16 + lg * 4 + r) * PSTR + nt * 16 + l15] = acc[mt][nt][r];
        __syncthreads();

        // ---- activation: sum 8 partials, gates, state update ----
        {
            float g0 = 0.f, g1 = 0.f, g2 = 0.f, g3 = 0.f;
            #pragma unroll
            for (int p = 0; p < 8; ++p) {
                const float* row = &P[p][b_act * PSTR];
                g0 += row[j_act];
                g1 += row[8 + j_act];
                g2 += row[16 + j_act];
                g3 += row[24 + j_act];
            }
            float fg = fast_sigmoid(g0 + bfv);
            float ig = fast_sigmoid(g1 + biv);
            float gg = fast_tanh(g2 + bgv);
            float og = fast_sigmoid(g3 + bov);
            c_state = fg * c_state + ig * gg;
            float hv = og * fast_tanh(c_state);
            h_last = hv;
            out[((size_t)t * BB + b_act) * HH + wg * 8 + j_act] = hv;
            if constexpr (MODE == 1) {
                // publish h(t) for step t+1: one self-validating dword
                store_coh4(hbuf32 + (size_t)((t + 1) & 1) * HB_ELEMS + wg * 512 + tid,
                           ((unsigned)(t + 1) << 16) | f2bf(hv));
            }
        }
        __syncthreads();   // protect P reuse at t+1
    }

    // ---- hT, cT ----
    {
        size_t base = (size_t)TT * BB * HH;
        out[base + (size_t)b_act * HH + wg * 8 + j_act] = h_last;
        out[base + BB * HH + (size_t)b_act * HH + wg * 8 + j_act] = c_state;
    }
}

extern "C" void kernel_launch(void* const* d_in, const int* in_sizes, int n_in,
                              void* d_out, int out_size, void* d_ws, size_t ws_size,
                              hipStream_t stream) {
    const float* x   = (const float*)d_in[0];
    const float* Wf  = (const float*)d_in[1];
    const float* bf_ = (const float*)d_in[2];
    const float* Wi  = (const float*)d_in[3];
    const float* bi_ = (const float*)d_in[4];
    const float* Wg  = (const float*)d_in[5];
    const float* bg_ = (const float*)d_in[6];
    const float* Wo  = (const float*)d_in[7];
    const float* bo_ = (const float*)d_in[8];
    float* out = (float*)d_out;
    unsigned* hbuf32 = (unsigned*)d_ws;

    const size_t need = (size_t)2 * HB_ELEMS * sizeof(unsigned);   // 256 KB

    if (ws_size >= need) {
        hipFuncSetAttribute((const void*)lstm_kernel<1>,
                            hipFuncAttributeMaxDynamicSharedMemorySize, LDS_BYTES);
        lstm_kernel<1><<<NWG, NTH, LDS_BYTES, stream>>>(x, Wf, bf_, Wi, bi_, Wg, bg_,
                                                        Wo, bo_, out, hbuf32, 0, TT);
    } else {
        hipFuncSetAttribute((const void*)lstm_kernel<2>,
                            hipFuncAttributeMaxDynamicSharedMemorySize, LDS_BYTES);
        for (int t = 0; t < TT; ++t)
            lstm_kernel<2><<<NWG, NTH, LDS_BYTES, stream>>>(x, Wf, bf_, Wi, bi_, Wg, bg_,
                                                            Wo, bo_, out, hbuf32, t, t + 1);
    }
}